// Round 9
// baseline (261.321 us; speedup 1.0000x reference)
//
#include <hip/hip_runtime.h>
#include <math.h>

#define Bb 16
#define Nn 2048
#define Dd 512
#define Kk 8

constexpr float TAU = 0.07f;
constexpr float EPSc = 1e-6f;
constexpr float LN_EPS = 1e-5f;
constexpr float NORM_EPS = 1e-12f;
constexpr float SCALE = 0.04419417382415922f; // 1/sqrt(512)

// output layout (floats)
constexpr size_t OUT_FFG  = 0;
constexpr size_t OUT_FBG  = (size_t)Bb*Nn*Dd;
constexpr size_t OUT_PBG  = OUT_FBG + (size_t)Bb*Nn*Dd;
constexpr size_t OUT_SSEM = OUT_PBG + (size_t)Bb*Kk*Dd;
constexpr size_t OUT_LOSS = OUT_SSEM + (size_t)Bb*Nn;

// ws layout (floats)
constexpr int    NCH = 32;                                      // chunks of 64 tokens
constexpr size_t WS_PBPART = 0;                                 // B*NCH*K*D = 2M
constexpr size_t WS_SUMW   = WS_PBPART + (size_t)Bb*NCH*Kk*Dd;  // B*NCH*8
constexpr size_t WS_NF2    = WS_SUMW + (size_t)Bb*NCH*Kk;       // B*N
constexpr size_t WS_SF     = WS_NF2 + (size_t)Bb*Nn;            // B*N
constexpr size_t WS_M      = WS_SF + (size_t)Bb*Nn;             // B*64
constexpr size_t WS_IDEN   = WS_M + Bb*64;                      // B*K
constexpr size_t WS_INP    = WS_IDEN + Bb*Kk;                   // B*K
constexpr size_t WS_P1     = WS_INP + Bb*Kk;                    // B*K
constexpr size_t WS_FQN    = WS_P1 + Bb*Kk;                     // B*D
constexpr size_t WS_CP     = WS_FQN + (size_t)Bb*Dd;            // B*N*8
constexpr size_t WS_P5A    = WS_CP + (size_t)Bb*Nn*Kk;          // 512*2
constexpr size_t WS_P5B    = WS_P5A + 1024;                     // 512*2
constexpr size_t WS_TRB    = WS_P5B + 1024;                     // 16

__device__ __forceinline__ float dot4(float4 a, float4 b) {
    return a.x*b.x + a.y*b.y + a.z*b.z + a.w*b.w;
}

// ============ K1: dots + exp + p~ partials (64 tok/block, 16 waves) ============
__global__ __launch_bounds__(1024, 8) void k1_scores(const float* __restrict__ f_raw,
                                                     const float* __restrict__ q_bg,
                                                     float* __restrict__ ws) {
    int b = blockIdx.x >> 5;
    int chunk = blockIdx.x & 31;
    int tok0 = chunk * 64;
    int tid = threadIdx.x, lane = tid & 63, wave = tid >> 6;   // 16 waves
    __shared__ float part[16][64][12];
    __shared__ float wlds[64][8];
    __shared__ float pacc[512][8];
    int dw = __builtin_amdgcn_readfirstlane(wave * 32);
    const float* qb = q_bg + dw;                                // wave-uniform -> s_load
    const float* ftok = f_raw + ((size_t)b*Nn + tok0 + lane)*Dd + dw;

    float a[8] = {0,0,0,0,0,0,0,0};
    float nf2 = 0.f, sf = 0.f;
    #pragma unroll
    for (int cc = 0; cc < 8; ++cc) {
        float4 f4 = *(const float4*)(ftok + cc*4);
        const float* qd = qb + cc*4;
        #pragma unroll
        for (int k = 0; k < 8; ++k) {
            float4 q4 = *(const float4*)(qd + k*Dd);
            a[k] += dot4(f4, q4);
        }
        nf2 += dot4(f4, f4);
        sf  += f4.x + f4.y + f4.z + f4.w;
    }
    *(float4*)&part[wave][lane][0] = make_float4(a[0],a[1],a[2],a[3]);
    *(float4*)&part[wave][lane][4] = make_float4(a[4],a[5],a[6],a[7]);
    *(float2*)&part[wave][lane][8] = make_float2(nf2, sf);
    __syncthreads();
    if (wave == 0) {
        float A[8] = {0,0,0,0,0,0,0,0};
        float n2 = 0.f, s1 = 0.f;
        #pragma unroll
        for (int w = 0; w < 16; ++w) {
            float4 p0 = *(const float4*)&part[w][lane][0];
            float4 p1 = *(const float4*)&part[w][lane][4];
            float2 p2 = *(const float2*)&part[w][lane][8];
            A[0]+=p0.x; A[1]+=p0.y; A[2]+=p0.z; A[3]+=p0.w;
            A[4]+=p1.x; A[5]+=p1.y; A[6]+=p1.z; A[7]+=p1.w;
            n2 += p2.x; s1 += p2.y;
        }
        size_t n = (size_t)b*Nn + tok0 + lane;
        ws[WS_NF2 + n] = n2;
        ws[WS_SF + n]  = s1;
        float w8[8];
        #pragma unroll
        for (int k = 0; k < 8; ++k) w8[k] = expf(A[k]*SCALE);
        *(float4*)&wlds[lane][0] = make_float4(w8[0],w8[1],w8[2],w8[3]);
        *(float4*)&wlds[lane][4] = make_float4(w8[4],w8[5],w8[6],w8[7]);
        float sw[8];
        #pragma unroll
        for (int k = 0; k < 8; ++k) sw[k] = w8[k];
        #pragma unroll
        for (int off = 32; off >= 1; off >>= 1) {
            #pragma unroll
            for (int k = 0; k < 8; ++k) sw[k] += __shfl_xor(sw[k], off, 64);
        }
        if (lane == 0) {
            #pragma unroll
            for (int k = 0; k < 8; ++k)
                ws[WS_SUMW + (size_t)(b*NCH + chunk)*8 + k] = sw[k];
        }
    }
    __syncthreads();
    // phase B: p~ partials; thread -> (d, token-half)
    int d = tid & 511;
    int half = tid >> 9;
    const float* fcol = f_raw + ((size_t)b*Nn + tok0 + half*32)*Dd + d;
    float acc[8] = {0,0,0,0,0,0,0,0};
    #pragma unroll 4
    for (int nn = 0; nn < 32; ++nn) {
        float f = fcol[(size_t)nn*Dd];
        float4 wa = *(const float4*)&wlds[half*32 + nn][0];
        float4 wb = *(const float4*)&wlds[half*32 + nn][4];
        acc[0]+=wa.x*f; acc[1]+=wa.y*f; acc[2]+=wa.z*f; acc[3]+=wa.w*f;
        acc[4]+=wb.x*f; acc[5]+=wb.y*f; acc[6]+=wb.z*f; acc[7]+=wb.w*f;
    }
    if (half == 1) {
        *(float4*)&pacc[d][0] = make_float4(acc[0],acc[1],acc[2],acc[3]);
        *(float4*)&pacc[d][4] = make_float4(acc[4],acc[5],acc[6],acc[7]);
    }
    __syncthreads();
    if (half == 0) {
        float4 q0 = *(const float4*)&pacc[d][0];
        float4 q1 = *(const float4*)&pacc[d][4];
        acc[0]+=q0.x; acc[1]+=q0.y; acc[2]+=q0.z; acc[3]+=q0.w;
        acc[4]+=q1.x; acc[5]+=q1.y; acc[6]+=q1.z; acc[7]+=q1.w;
        #pragma unroll
        for (int k = 0; k < 8; ++k)
            ws[WS_PBPART + ((size_t)(b*NCH + chunk)*8 + k)*Dd + d] = acc[k];
    }
}

// ============ K3b1: reduce partials -> normalized p_bg (128 blocks) ============
__global__ __launch_bounds__(256) void k3b1_reduce(float* __restrict__ ws,
                                                   float* __restrict__ out_pbg) {
    int b = blockIdx.x, k = blockIdx.y;
    int tid = threadIdx.x;
    float v = ws[WS_SUMW + (size_t)(b*NCH + (tid & 31))*8 + k];
    #pragma unroll
    for (int off = 16; off >= 1; off >>= 1) v += __shfl_xor(v, off, 64);
    float swt = 1.f / v;
    float s0 = 0.f, s1 = 0.f;
    #pragma unroll 4
    for (int ns = 0; ns < NCH; ++ns) {
        const float* p = ws + WS_PBPART + ((size_t)(b*NCH + ns)*8 + k)*Dd;
        s0 += p[tid];
        s1 += p[tid + 256];
    }
    out_pbg[(size_t)b*Kk*Dd + (size_t)k*Dd + tid]       = s0*swt;
    out_pbg[(size_t)b*Kk*Dd + (size_t)k*Dd + tid + 256] = s1*swt;
}

// ============ K3b2: M, iden, inp, P1, fqn from p_bg (16 blocks) ============
__global__ __launch_bounds__(256) void k3b2_stats(float* __restrict__ ws,
                                                  const float* __restrict__ pbg,
                                                  const float* __restrict__ f_q) {
    int b = blockIdx.x, tid = threadIdx.x;
    int lane = tid & 63, wave = tid >> 6;
    __shared__ float pb[Kk*Dd];
    __shared__ float mseg[64][4];
    __shared__ float p1seg[8][8];
    __shared__ float red[4];
    for (int e = tid; e < Kk*Dd; e += 256) pb[e] = pbg[(size_t)b*Kk*Dd + e];
    float q0 = f_q[b*Dd + tid], q1 = f_q[b*Dd + 256 + tid];
    float p2 = q0*q0 + q1*q1;
    #pragma unroll
    for (int off = 32; off >= 1; off >>= 1) p2 += __shfl_xor(p2, off, 64);
    if (lane == 0) red[wave] = p2;
    __syncthreads();
    float invq = 1.f/fmaxf(sqrtf(red[0]+red[1]+red[2]+red[3]), NORM_EPS);
    ws[WS_FQN + b*Dd + tid] = q0*invq;
    ws[WS_FQN + b*Dd + 256 + tid] = q1*invq;
    {
        int pair = tid >> 2, seg = tid & 3;
        int i = pair >> 3, j = pair & 7;
        float s = 0.f;
        for (int d = seg*128; d < seg*128 + 128; ++d) s += pb[i*Dd + d]*pb[j*Dd + d];
        mseg[pair][seg] = s;
    }
    if (tid < 64) {
        int k = tid >> 3, sg = tid & 7;
        float s1 = 0.f;
        for (int d = sg*64; d < sg*64 + 64; ++d) s1 += pb[k*Dd + d];
        p1seg[k][sg] = s1;
    }
    __syncthreads();
    if (tid < 64) {
        float m = mseg[tid][0] + mseg[tid][1] + mseg[tid][2] + mseg[tid][3];
        ws[WS_M + b*64 + tid] = m;
        if ((tid >> 3) == (tid & 7)) {
            int k = tid & 7;
            ws[WS_IDEN + b*Kk + k] = 1.f/(m + EPSc);
            ws[WS_INP + b*Kk + k] = 1.f/fmaxf(sqrtf(m), NORM_EPS);
        }
    }
    if (tid < 8) {
        float s1 = 0.f;
        #pragma unroll
        for (int sg = 0; sg < 8; ++sg) s1 += p1seg[tid][sg];
        ws[WS_P1 + b*Kk + tid] = s1;
    }
}

// ============ K5: dots -> scalars -> stream (64 tok/block, 16 waves) ============
__global__ __launch_bounds__(1024, 8) void k5_main(
    const float* __restrict__ f_raw, const int* __restrict__ gt_mask,
    const float* __restrict__ alpha_p, const float* __restrict__ ln_w,
    const float* __restrict__ ln_b, const float* __restrict__ pbg,
    float* __restrict__ ws, float* __restrict__ out_ffg,
    float* __restrict__ out_fbg, float* __restrict__ out_ssem)
{
    int b = blockIdx.x >> 5;
    int chunk = blockIdx.x & 31;
    int tok0 = chunk * 64;
    int tid = threadIdx.x, lane = tid & 63, wave = tid >> 6;   // 16 waves
    __shared__ float part[16][64][8];
    __shared__ float scl[64][12];
    __shared__ float Ml[64];
    __shared__ float idenl[8], inpl[8], p1l[8];
    __shared__ float al[16][2];
    if (tid < 64) Ml[tid] = ws[WS_M + b*64 + tid];
    else if (tid < 88) {
        int g = (tid-64) >> 3, k = (tid-64) & 7;
        if      (g == 0) idenl[k] = ws[WS_IDEN + b*8 + k];
        else if (g == 1) inpl[k]  = ws[WS_INP  + b*8 + k];
        else             p1l[k]   = ws[WS_P1   + b*8 + k];
    }
    int dw = __builtin_amdgcn_readfirstlane(wave * 32);
    const float* pbb = pbg + (size_t)b*Kk*Dd + dw;              // wave-uniform -> s_load
    const float* ftok = f_raw + ((size_t)b*Nn + tok0 + lane)*Dd + dw;

    float a[8] = {0,0,0,0,0,0,0,0};
    #pragma unroll
    for (int cc = 0; cc < 8; ++cc) {
        float4 f4 = *(const float4*)(ftok + cc*4);
        const float* pd = pbb + cc*4;
        #pragma unroll
        for (int k = 0; k < 8; ++k) {
            float4 p4 = *(const float4*)(pd + k*Dd);
            a[k] += dot4(f4, p4);
        }
    }
    *(float4*)&part[wave][lane][0] = make_float4(a[0],a[1],a[2],a[3]);
    *(float4*)&part[wave][lane][4] = make_float4(a[4],a[5],a[6],a[7]);
    __syncthreads();
    if (wave == 0) {
        float A[8] = {0,0,0,0,0,0,0,0};
        #pragma unroll
        for (int w = 0; w < 16; ++w) {
            float4 p0 = *(const float4*)&part[w][lane][0];
            float4 p1 = *(const float4*)&part[w][lane][4];
            A[0]+=p0.x; A[1]+=p0.y; A[2]+=p0.z; A[3]+=p0.w;
            A[4]+=p1.x; A[5]+=p1.y; A[6]+=p1.z; A[7]+=p1.w;
        }
        size_t n = (size_t)b*Nn + tok0 + lane;
        float nf2 = ws[WS_NF2 + n];
        float sf  = ws[WS_SF + n];
        float alpha = alpha_p[0];
        float coef[8], sca = 0.f, sp1 = 0.f;
        #pragma unroll
        for (int k = 0; k < 8; ++k) {
            coef[k] = A[k]*idenl[k];
            sca += coef[k]*A[k];
            sp1 += coef[k]*p1l[k];
        }
        float quad = 0.f;
        #pragma unroll
        for (int i = 0; i < 8; ++i) {
            float ti = 0.f;
            #pragma unroll
            for (int j = 0; j < 8; ++j) ti += Ml[i*8+j]*coef[j];
            quad += coef[i]*ti;
        }
        float sx  = sf - alpha*sp1;
        float sxx = nf2 - 2.f*alpha*sca + alpha*alpha*quad;
        float mu  = sx*(1.f/Dd);
        float var = sxx*(1.f/Dd) - mu*mu;
        float rstd = 1.f/sqrtf(fmaxf(var, 0.f) + LN_EPS);
        float invnf = 1.f/fmaxf(sqrtf(nf2), NORM_EPS);
        float cmin = 1e30f;
        #pragma unroll
        for (int k = 0; k < 8; ++k) cmin = fminf(cmin, 1.f - A[k]*invnf*inpl[k]);
        float invnb = 1.f/fmaxf(sqrtf(quad), NORM_EPS);
        float inb2 = invnb*invnb;
        float gnn = quad*inb2;
        float dsum = gnn*gnn;
        *(float4*)&scl[lane][0] = make_float4(coef[0],coef[1],coef[2],coef[3]);
        *(float4*)&scl[lane][4] = make_float4(coef[4],coef[5],coef[6],coef[7]);
        *(float2*)&scl[lane][8] = make_float2(mu, rstd);
        *(float4*)(ws + WS_CP + n*8)     = make_float4(coef[0]*invnb,coef[1]*invnb,coef[2]*invnb,coef[3]*invnb);
        *(float4*)(ws + WS_CP + n*8 + 4) = make_float4(coef[4]*invnb,coef[5]*invnb,coef[6]*invnb,coef[7]*invnb);
        float csum = cmin;
        #pragma unroll
        for (int off = 32; off >= 1; off >>= 1) {
            csum += __shfl_xor(csum, off, 64);
            dsum += __shfl_xor(dsum, off, 64);
        }
        if (lane == 0) {
            ws[WS_P5A + (size_t)blockIdx.x*2 + 0] = csum;
            ws[WS_P5A + (size_t)blockIdx.x*2 + 1] = dsum;
        }
    }
    __syncthreads();
    // phase B: stream; 16 waves x 4 tokens, two 256-d halves sequentially
    float alpha = alpha_p[0];
    const float* pbB = pbg + (size_t)b*Kk*Dd;
    float ng2h[4], dqh[4];
    {
        int d0 = lane*4;
        float4 pbr[8];
        #pragma unroll
        for (int k = 0; k < 8; ++k) pbr[k] = *(const float4*)(pbB + k*Dd + d0);
        float4 w4 = *(const float4*)(ln_w + d0);
        float4 b4 = *(const float4*)(ln_b + d0);
        float4 q4 = *(const float4*)(ws + WS_FQN + b*Dd + d0);
        #pragma unroll
        for (int t = 0; t < 4; ++t) {
            int lt = wave*4 + t;
            float4 cA = *(const float4*)&scl[lt][0];
            float4 cB = *(const float4*)&scl[lt][4];
            float2 mr = *(const float2*)&scl[lt][8];
            size_t rowoff = ((size_t)b*Nn + tok0 + lt)*Dd;
            float4 fv = *(const float4*)(f_raw + rowoff + d0);
            float4 fb;
            fb.x = cA.x*pbr[0].x + cA.y*pbr[1].x + cA.z*pbr[2].x + cA.w*pbr[3].x
                 + cB.x*pbr[4].x + cB.y*pbr[5].x + cB.z*pbr[6].x + cB.w*pbr[7].x;
            fb.y = cA.x*pbr[0].y + cA.y*pbr[1].y + cA.z*pbr[2].y + cA.w*pbr[3].y
                 + cB.x*pbr[4].y + cB.y*pbr[5].y + cB.z*pbr[6].y + cB.w*pbr[7].y;
            fb.z = cA.x*pbr[0].z + cA.y*pbr[1].z + cA.z*pbr[2].z + cA.w*pbr[3].z
                 + cB.x*pbr[4].z + cB.y*pbr[5].z + cB.z*pbr[6].z + cB.w*pbr[7].z;
            fb.w = cA.x*pbr[0].w + cA.y*pbr[1].w + cA.z*pbr[2].w + cA.w*pbr[3].w
                 + cB.x*pbr[4].w + cB.y*pbr[5].w + cB.z*pbr[6].w + cB.w*pbr[7].w;
            *(float4*)(out_fbg + rowoff + d0) = fb;
            float4 g;
            g.x = (fv.x - alpha*fb.x - mr.x)*mr.y*w4.x + b4.x;
            g.y = (fv.y - alpha*fb.y - mr.x)*mr.y*w4.y + b4.y;
            g.z = (fv.z - alpha*fb.z - mr.x)*mr.y*w4.z + b4.z;
            g.w = (fv.w - alpha*fb.w - mr.x)*mr.y*w4.w + b4.w;
            *(float4*)(out_ffg + rowoff + d0) = g;
            ng2h[t] = dot4(g, g);
            dqh[t]  = dot4(g, q4);
        }
    }
    float align_s = 0.f, align_c = 0.f;
    {
        int d0 = 256 + lane*4;
        float4 pbr[8];
        #pragma unroll
        for (int k = 0; k < 8; ++k) pbr[k] = *(const float4*)(pbB + k*Dd + d0);
        float4 w4 = *(const float4*)(ln_w + d0);
        float4 b4 = *(const float4*)(ln_b + d0);
        float4 q4 = *(const float4*)(ws + WS_FQN + b*Dd + d0);
        #pragma unroll
        for (int t = 0; t < 4; ++t) {
            int lt = wave*4 + t;
            size_t n = (size_t)b*Nn + tok0 + lt;
            float4 cA = *(const float4*)&scl[lt][0];
            float4 cB = *(const float4*)&scl[lt][4];
            float2 mr = *(const float2*)&scl[lt][8];
            size_t rowoff = n*(size_t)Dd;
            float4 fv = *(const float4*)(f_raw + rowoff + d0);
            float4 fb;
            fb.x = cA.x*pbr[0].x + cA.y*pbr[1].x + cA.z*pbr[2].x + cA.w*pbr[3].x
                 + cB.x*pbr[4].x + cB.y*pbr[5].x + cB.z*pbr[6].x + cB.w*pbr[7].x;
            fb.y = cA.x*pbr[0].y + cA.y*pbr[1].y + cA.z*pbr[2].y + cA.w*pbr[3].y
                 + cB.x*pbr[4].y + cB.y*pbr[5].y + cB.z*pbr[6].y + cB.w*pbr[7].y;
            fb.z = cA.x*pbr[0].z + cA.y*pbr[1].z + cA.z*pbr[2].z + cA.w*pbr[3].z
                 + cB.x*pbr[4].z + cB.y*pbr[5].z + cB.z*pbr[6].z + cB.w*pbr[7].z;
            fb.w = cA.x*pbr[0].w + cA.y*pbr[1].w + cA.z*pbr[2].w + cA.w*pbr[3].w
                 + cB.x*pbr[4].w + cB.y*pbr[5].w + cB.z*pbr[6].w + cB.w*pbr[7].w;
            *(float4*)(out_fbg + rowoff + d0) = fb;
            float4 g;
            g.x = (fv.x - alpha*fb.x - mr.x)*mr.y*w4.x + b4.x;
            g.y = (fv.y - alpha*fb.y - mr.x)*mr.y*w4.y + b4.y;
            g.z = (fv.z - alpha*fb.z - mr.x)*mr.y*w4.z + b4.z;
            g.w = (fv.w - alpha*fb.w - mr.x)*mr.y*w4.w + b4.w;
            *(float4*)(out_ffg + rowoff + d0) = g;
            float ng2 = ng2h[t] + dot4(g, g);
            float dq  = dqh[t]  + dot4(g, q4);
            #pragma unroll
            for (int off = 32; off >= 1; off >>= 1) {
                ng2 += __shfl_xor(ng2, off, 64);
                dq  += __shfl_xor(dq,  off, 64);
            }
            float sim = dq * (1.f/fmaxf(sqrtf(ng2), NORM_EPS));
            float ssem = 1.f/(1.f + expf(-sim*(1.f/TAU)));
            if (lane == 0) {
                out_ssem[n] = ssem;
                if (gt_mask[n] != 0) { align_s += -logf(fmaxf(ssem, EPSc)); align_c += 1.f; }
            }
        }
    }
    if (lane == 0) { al[wave][0] = align_s; al[wave][1] = align_c; }
    __syncthreads();
    if (tid == 0) {
        float as = 0.f, ac = 0.f;
        #pragma unroll
        for (int w = 0; w < 16; ++w) { as += al[w][0]; ac += al[w][1]; }
        ws[WS_P5B + (size_t)blockIdx.x*2 + 0] = as;
        ws[WS_P5B + (size_t)blockIdx.x*2 + 1] = ac;
    }
}

// ============ K6s: per-batch S = sum cp cp^T, then tr((M S)^2) ============
__global__ __launch_bounds__(256) void k6s_gram(float* __restrict__ ws) {
    int b = blockIdx.x, tid = threadIdx.x;
    __shared__ float cps[256*8];
    __shared__ float Sred[4][64];
    __shared__ float Sfull[64];
    __shared__ float Alds[64];
    __shared__ float Mlds[64];
    int pr = tid & 63, g = tid >> 6;
    int i = pr >> 3, j = pr & 7;
    float s = 0.f;
    for (int tile = 0; tile < 8; ++tile) {
        __syncthreads();
        #pragma unroll
        for (int q = 0; q < 2; ++q)
            *(float4*)&cps[tid*8 + q*4] =
                *(const float4*)(ws + WS_CP + ((size_t)b*Nn + tile*256)*8 + tid*8 + q*4);
        __syncthreads();
        for (int nn = g*64; nn < g*64 + 64; ++nn)
            s += cps[nn*8 + i]*cps[nn*8 + j];
    }
    Sred[g][pr] = s;
    if (tid < 64) Mlds[tid] = ws[WS_M + b*64 + tid];
    __syncthreads();
    if (tid < 64) Sfull[tid] = Sred[0][tid]+Sred[1][tid]+Sred[2][tid]+Sred[3][tid];
    __syncthreads();
    if (tid < 64) {
        int ii = tid >> 3, jj = tid & 7;
        float a = 0.f;
        #pragma unroll
        for (int k = 0; k < 8; ++k) a += Mlds[ii*8+k]*Sfull[k*8+jj];
        Alds[tid] = a;
    }
    __syncthreads();
    if (tid < 64) {
        float p = Alds[tid]*Alds[(tid & 7)*8 + (tid >> 3)];
        #pragma unroll
        for (int off = 32; off >= 1; off >>= 1) p += __shfl_xor(p, off, 64);
        if (tid == 0) ws[WS_TRB + b] = p;
    }
}

// ============ K7: finalize losses ============
__global__ __launch_bounds__(256) void k7_final(const float* __restrict__ ws,
                                                float* __restrict__ out_loss) {
    int tid = threadIdx.x, lane = tid & 63, wave = tid >> 6;
    __shared__ double red[4][4];
    double c = 0.0, dg = 0.0, as = 0.0, ac = 0.0;
    for (int idx = tid; idx < 512; idx += 256) {
        c  += (double)ws[WS_P5A + idx*2 + 0];
        dg += (double)ws[WS_P5A + idx*2 + 1];
        as += (double)ws[WS_P5B + idx*2 + 0];
        ac += (double)ws[WS_P5B + idx*2 + 1];
    }
    #pragma unroll
    for (int off = 32; off >= 1; off >>= 1) {
        c  += __shfl_xor(c,  off, 64);
        dg += __shfl_xor(dg, off, 64);
        as += __shfl_xor(as, off, 64);
        ac += __shfl_xor(ac, off, 64);
    }
    if (lane == 0) { red[wave][0]=c; red[wave][1]=dg; red[wave][2]=as; red[wave][3]=ac; }
    __syncthreads();
    if (tid == 0) {
        double ct=0, dgt=0, ast=0, act=0, trt=0;
        for (int w = 0; w < 4; ++w) { ct+=red[w][0]; dgt+=red[w][1]; ast+=red[w][2]; act+=red[w][3]; }
        for (int b = 0; b < Bb; ++b) trt += (double)ws[WS_TRB + b];
        out_loss[0] = (float)(ct / (double)((size_t)Bb*Nn));
        out_loss[1] = (float)((trt - dgt) / ((double)Bb*(double)Nn*(double)Nn));
        out_loss[2] = (float)(act > 0.0 ? ast / (act > 1.0 ? act : 1.0) : 0.0);
    }
}

extern "C" void kernel_launch(void* const* d_in, const int* in_sizes, int n_in,
                              void* d_out, int out_size, void* d_ws, size_t ws_size,
                              hipStream_t stream) {
    (void)in_sizes; (void)n_in; (void)out_size; (void)ws_size;
    const float* f_raw   = (const float*)d_in[0];
    const float* f_q     = (const float*)d_in[1];
    const int*   gt_mask = (const int*)d_in[2];
    const float* q_bg    = (const float*)d_in[3];
    const float* alpha   = (const float*)d_in[4];
    const float* ln_w    = (const float*)d_in[5];
    const float* ln_b    = (const float*)d_in[6];
    float* out = (float*)d_out;
    float* ws  = (float*)d_ws;

    k1_scores<<<Bb*NCH, 1024, 0, stream>>>(f_raw, q_bg, ws);
    k3b1_reduce<<<dim3(Bb, Kk), 256, 0, stream>>>(ws, out + OUT_PBG);
    k3b2_stats<<<Bb, 256, 0, stream>>>(ws, out + OUT_PBG, f_q);
    k5_main<<<Bb*NCH, 1024, 0, stream>>>(f_raw, gt_mask, alpha, ln_w, ln_b,
                                         out + OUT_PBG, ws,
                                         out + OUT_FFG, out + OUT_FBG, out + OUT_SSEM);
    k6s_gram<<<Bb, 256, 0, stream>>>(ws);
    k7_final<<<1, 256, 0, stream>>>(ws, out + OUT_LOSS);
}

// Round 10
// 117.883 us; speedup vs baseline: 2.2168x; 2.2168x over previous
//
#include <hip/hip_runtime.h>
#include <math.h>

#define Bb 16
#define Nn 2048
#define Dd 512
#define Kk 8

constexpr float TAU = 0.07f;
constexpr float EPSc = 1e-6f;
constexpr float LN_EPS = 1e-5f;
constexpr float NORM_EPS = 1e-12f;
constexpr float SCALE = 0.04419417382415922f; // 1/sqrt(512)

// output layout (floats)
constexpr size_t OUT_FFG  = 0;
constexpr size_t OUT_FBG  = (size_t)Bb*Nn*Dd;
constexpr size_t OUT_PBG  = OUT_FBG + (size_t)Bb*Nn*Dd;
constexpr size_t OUT_SSEM = OUT_PBG + (size_t)Bb*Kk*Dd;
constexpr size_t OUT_LOSS = OUT_SSEM + (size_t)Bb*Nn;

// ws layout (floats)
constexpr int    NCH = 64;                                      // chunks of 32 tokens
constexpr size_t WS_PBPART = 0;                                 // B*NCH*K*D = 4M
constexpr size_t WS_SUMW   = WS_PBPART + (size_t)Bb*NCH*Kk*Dd;  // B*NCH*8
constexpr size_t WS_NF2    = WS_SUMW + (size_t)Bb*NCH*Kk;       // B*N
constexpr size_t WS_SF     = WS_NF2 + (size_t)Bb*Nn;            // B*N
constexpr size_t WS_M      = WS_SF + (size_t)Bb*Nn;             // B*64
constexpr size_t WS_IDEN   = WS_M + Bb*64;                      // B*K
constexpr size_t WS_INP    = WS_IDEN + Bb*Kk;                   // B*K
constexpr size_t WS_P1     = WS_INP + Bb*Kk;                    // B*K
constexpr size_t WS_FQN    = WS_P1 + Bb*Kk;                     // B*D
constexpr size_t WS_CP     = WS_FQN + (size_t)Bb*Dd;            // B*N*8
constexpr size_t WS_P5A    = WS_CP + (size_t)Bb*Nn*Kk;          // 1024*2
constexpr size_t WS_P5B    = WS_P5A + 2048;                     // 1024*2
constexpr size_t WS_TRB    = WS_P5B + 2048;                     // 16

__device__ __forceinline__ float dot4(float4 a, float4 b) {
    return a.x*b.x + a.y*b.y + a.z*b.z + a.w*b.w;
}

// ============ K1: dots + exp + p~ partials (32 tok/block, 8 waves, grid 1024) ============
__global__ __launch_bounds__(512, 4) void k1_scores(const float* __restrict__ f_raw,
                                                    const float* __restrict__ q_bg,
                                                    float* __restrict__ ws) {
    int b = blockIdx.x >> 6;
    int chunk = blockIdx.x & 63;
    int tok0 = chunk * 32;
    int tid = threadIdx.x, lane = tid & 63, wave = tid >> 6;   // 8 waves
    __shared__ float qls[Kk*Dd];          // 16 KB
    __shared__ float part[8][32][12];     // 12 KB
    __shared__ float wlds[32][8];         // 1 KB
    for (int e = tid; e < Kk*Dd; e += 512) qls[e] = q_bg[e];
    __syncthreads();
    int tok = lane & 31, half = lane >> 5;
    int dwl = wave*64 + half*32;
    const float* ftok = f_raw + ((size_t)b*Nn + tok0 + tok)*Dd + dwl;

    float a[8] = {0,0,0,0,0,0,0,0};
    float nf2 = 0.f, sf = 0.f;
    #pragma unroll
    for (int cc = 0; cc < 8; ++cc) {
        float4 f4 = *(const float4*)(ftok + cc*4);
        int qo = dwl + cc*4;
        #pragma unroll
        for (int k = 0; k < 8; ++k) {
            float4 q4 = *(const float4*)&qls[k*Dd + qo];
            a[k] += dot4(f4, q4);
        }
        nf2 += dot4(f4, f4);
        sf  += f4.x + f4.y + f4.z + f4.w;
    }
    #pragma unroll
    for (int k = 0; k < 8; ++k) a[k] += __shfl_xor(a[k], 32, 64);
    nf2 += __shfl_xor(nf2, 32, 64);
    sf  += __shfl_xor(sf, 32, 64);
    if (lane < 32) {
        *(float4*)&part[wave][tok][0] = make_float4(a[0],a[1],a[2],a[3]);
        *(float4*)&part[wave][tok][4] = make_float4(a[4],a[5],a[6],a[7]);
        *(float2*)&part[wave][tok][8] = make_float2(nf2, sf);
    }
    __syncthreads();
    if (wave == 0 && lane < 32) {
        float A[8] = {0,0,0,0,0,0,0,0};
        float n2 = 0.f, s1 = 0.f;
        #pragma unroll
        for (int w = 0; w < 8; ++w) {
            float4 p0 = *(const float4*)&part[w][lane][0];
            float4 p1 = *(const float4*)&part[w][lane][4];
            float2 p2 = *(const float2*)&part[w][lane][8];
            A[0]+=p0.x; A[1]+=p0.y; A[2]+=p0.z; A[3]+=p0.w;
            A[4]+=p1.x; A[5]+=p1.y; A[6]+=p1.z; A[7]+=p1.w;
            n2 += p2.x; s1 += p2.y;
        }
        size_t n = (size_t)b*Nn + tok0 + lane;
        ws[WS_NF2 + n] = n2;
        ws[WS_SF + n]  = s1;
        float w8[8];
        #pragma unroll
        for (int k = 0; k < 8; ++k) w8[k] = expf(A[k]*SCALE);
        *(float4*)&wlds[lane][0] = make_float4(w8[0],w8[1],w8[2],w8[3]);
        *(float4*)&wlds[lane][4] = make_float4(w8[4],w8[5],w8[6],w8[7]);
        float sw[8];
        #pragma unroll
        for (int k = 0; k < 8; ++k) sw[k] = w8[k];
        #pragma unroll
        for (int off = 16; off >= 1; off >>= 1) {
            #pragma unroll
            for (int k = 0; k < 8; ++k) sw[k] += __shfl_xor(sw[k], off, 64);
        }
        if (lane == 0) {
            #pragma unroll
            for (int k = 0; k < 8; ++k)
                ws[WS_SUMW + (size_t)(b*NCH + chunk)*8 + k] = sw[k];
        }
    }
    __syncthreads();
    // phase B: p~ partials; thread -> d (0..511), loop 32 tokens
    int d = tid;
    const float* fcol = f_raw + ((size_t)b*Nn + tok0)*Dd + d;
    float acc[8] = {0,0,0,0,0,0,0,0};
    #pragma unroll 4
    for (int nn = 0; nn < 32; ++nn) {
        float f = fcol[(size_t)nn*Dd];
        float4 wa = *(const float4*)&wlds[nn][0];
        float4 wb = *(const float4*)&wlds[nn][4];
        acc[0]+=wa.x*f; acc[1]+=wa.y*f; acc[2]+=wa.z*f; acc[3]+=wa.w*f;
        acc[4]+=wb.x*f; acc[5]+=wb.y*f; acc[6]+=wb.z*f; acc[7]+=wb.w*f;
    }
    #pragma unroll
    for (int k = 0; k < 8; ++k)
        ws[WS_PBPART + ((size_t)(b*NCH + chunk)*8 + k)*Dd + d] = acc[k];
}

// ============ K3b1: reduce partials -> normalized p_bg (128 blocks) ============
__global__ __launch_bounds__(256) void k3b1_reduce(float* __restrict__ ws,
                                                   float* __restrict__ out_pbg) {
    int b = blockIdx.x, k = blockIdx.y;
    int tid = threadIdx.x;
    float v = ws[WS_SUMW + (size_t)(b*NCH + (tid & 63))*8 + k];
    #pragma unroll
    for (int off = 32; off >= 1; off >>= 1) v += __shfl_xor(v, off, 64);
    float swt = 1.f / v;
    float s0 = 0.f, s1 = 0.f;
    #pragma unroll 4
    for (int ns = 0; ns < NCH; ++ns) {
        const float* p = ws + WS_PBPART + ((size_t)(b*NCH + ns)*8 + k)*Dd;
        s0 += p[tid];
        s1 += p[tid + 256];
    }
    out_pbg[(size_t)b*Kk*Dd + (size_t)k*Dd + tid]       = s0*swt;
    out_pbg[(size_t)b*Kk*Dd + (size_t)k*Dd + tid + 256] = s1*swt;
}

// ============ K3b2: M, iden, inp, P1, fqn from p_bg (16 blocks) ============
__global__ __launch_bounds__(256) void k3b2_stats(float* __restrict__ ws,
                                                  const float* __restrict__ pbg,
                                                  const float* __restrict__ f_q) {
    int b = blockIdx.x, tid = threadIdx.x;
    int lane = tid & 63, wave = tid >> 6;
    __shared__ float pb[Kk*Dd];
    __shared__ float mseg[64][4];
    __shared__ float p1seg[8][8];
    __shared__ float red[4];
    for (int e = tid; e < Kk*Dd; e += 256) pb[e] = pbg[(size_t)b*Kk*Dd + e];
    float q0 = f_q[b*Dd + tid], q1 = f_q[b*Dd + 256 + tid];
    float p2 = q0*q0 + q1*q1;
    #pragma unroll
    for (int off = 32; off >= 1; off >>= 1) p2 += __shfl_xor(p2, off, 64);
    if (lane == 0) red[wave] = p2;
    __syncthreads();
    float invq = 1.f/fmaxf(sqrtf(red[0]+red[1]+red[2]+red[3]), NORM_EPS);
    ws[WS_FQN + b*Dd + tid] = q0*invq;
    ws[WS_FQN + b*Dd + 256 + tid] = q1*invq;
    {
        int pair = tid >> 2, seg = tid & 3;
        int i = pair >> 3, j = pair & 7;
        float s = 0.f;
        for (int d = seg*128; d < seg*128 + 128; ++d) s += pb[i*Dd + d]*pb[j*Dd + d];
        mseg[pair][seg] = s;
    }
    if (tid < 64) {
        int k = tid >> 3, sg = tid & 7;
        float s1 = 0.f;
        for (int d = sg*64; d < sg*64 + 64; ++d) s1 += pb[k*Dd + d];
        p1seg[k][sg] = s1;
    }
    __syncthreads();
    if (tid < 64) {
        float m = mseg[tid][0] + mseg[tid][1] + mseg[tid][2] + mseg[tid][3];
        ws[WS_M + b*64 + tid] = m;
        if ((tid >> 3) == (tid & 7)) {
            int k = tid & 7;
            ws[WS_IDEN + b*Kk + k] = 1.f/(m + EPSc);
            ws[WS_INP + b*Kk + k] = 1.f/fmaxf(sqrtf(m), NORM_EPS);
        }
    }
    if (tid < 8) {
        float s1 = 0.f;
        #pragma unroll
        for (int sg = 0; sg < 8; ++sg) s1 += p1seg[tid][sg];
        ws[WS_P1 + b*Kk + tid] = s1;
    }
}

// ============ K5: dots -> scalars -> stream (32 tok/block, 8 waves, grid 1024) ============
__global__ __launch_bounds__(512, 4) void k5_main(
    const float* __restrict__ f_raw, const int* __restrict__ gt_mask,
    const float* __restrict__ alpha_p, const float* __restrict__ ln_w,
    const float* __restrict__ ln_b, const float* __restrict__ pbg,
    float* __restrict__ ws, float* __restrict__ out_ffg,
    float* __restrict__ out_fbg, float* __restrict__ out_ssem)
{
    int b = blockIdx.x >> 6;
    int chunk = blockIdx.x & 63;
    int tok0 = chunk * 32;
    int tid = threadIdx.x, lane = tid & 63, wave = tid >> 6;   // 8 waves
    __shared__ float pls[Kk*Dd];         // 16 KB
    __shared__ float part[8][32][8];     // 8 KB
    __shared__ float scl[32][12];
    __shared__ float Ml[64];
    __shared__ float idenl[8], inpl[8], p1l[8];
    __shared__ float al[8][2];
    for (int e = tid; e < Kk*Dd; e += 512) pls[e] = pbg[(size_t)b*Kk*Dd + e];
    if (tid >= 512-96 && tid < 512-32) Ml[tid-(512-96)] = ws[WS_M + b*64 + (tid-(512-96))];
    else if (tid >= 512-32 && tid < 512-8) {
        int g = (tid-(512-32)) >> 3, k = (tid-(512-32)) & 7;
        if      (g == 0) idenl[k] = ws[WS_IDEN + b*8 + k];
        else if (g == 1) inpl[k]  = ws[WS_INP  + b*8 + k];
        else             p1l[k]   = ws[WS_P1   + b*8 + k];
    }
    __syncthreads();
    int tok = lane & 31, half = lane >> 5;
    int dwl = wave*64 + half*32;
    const float* ftok = f_raw + ((size_t)b*Nn + tok0 + tok)*Dd + dwl;

    float a[8] = {0,0,0,0,0,0,0,0};
    #pragma unroll
    for (int cc = 0; cc < 8; ++cc) {
        float4 f4 = *(const float4*)(ftok + cc*4);
        int po = dwl + cc*4;
        #pragma unroll
        for (int k = 0; k < 8; ++k) {
            float4 p4 = *(const float4*)&pls[k*Dd + po];
            a[k] += dot4(f4, p4);
        }
    }
    #pragma unroll
    for (int k = 0; k < 8; ++k) a[k] += __shfl_xor(a[k], 32, 64);
    if (lane < 32) {
        *(float4*)&part[wave][tok][0] = make_float4(a[0],a[1],a[2],a[3]);
        *(float4*)&part[wave][tok][4] = make_float4(a[4],a[5],a[6],a[7]);
    }
    __syncthreads();
    if (wave == 0) {
        float csum = 0.f, dsum = 0.f;
        if (lane < 32) {
            float A[8] = {0,0,0,0,0,0,0,0};
            #pragma unroll
            for (int w = 0; w < 8; ++w) {
                float4 p0 = *(const float4*)&part[w][lane][0];
                float4 p1 = *(const float4*)&part[w][lane][4];
                A[0]+=p0.x; A[1]+=p0.y; A[2]+=p0.z; A[3]+=p0.w;
                A[4]+=p1.x; A[5]+=p1.y; A[6]+=p1.z; A[7]+=p1.w;
            }
            size_t n = (size_t)b*Nn + tok0 + lane;
            float nf2 = ws[WS_NF2 + n];
            float sf  = ws[WS_SF + n];
            float alpha = alpha_p[0];
            float coef[8], sca = 0.f, sp1 = 0.f;
            #pragma unroll
            for (int k = 0; k < 8; ++k) {
                coef[k] = A[k]*idenl[k];
                sca += coef[k]*A[k];
                sp1 += coef[k]*p1l[k];
            }
            float quad = 0.f;
            #pragma unroll
            for (int i = 0; i < 8; ++i) {
                float ti = 0.f;
                #pragma unroll
                for (int j = 0; j < 8; ++j) ti += Ml[i*8+j]*coef[j];
                quad += coef[i]*ti;
            }
            float sx  = sf - alpha*sp1;
            float sxx = nf2 - 2.f*alpha*sca + alpha*alpha*quad;
            float mu  = sx*(1.f/Dd);
            float var = sxx*(1.f/Dd) - mu*mu;
            float rstd = 1.f/sqrtf(fmaxf(var, 0.f) + LN_EPS);
            float invnf = 1.f/fmaxf(sqrtf(nf2), NORM_EPS);
            float cmin = 1e30f;
            #pragma unroll
            for (int k = 0; k < 8; ++k) cmin = fminf(cmin, 1.f - A[k]*invnf*inpl[k]);
            float invnb = 1.f/fmaxf(sqrtf(quad), NORM_EPS);
            float inb2 = invnb*invnb;
            float gnn = quad*inb2;
            csum = cmin;
            dsum = gnn*gnn;
            *(float4*)&scl[lane][0] = make_float4(coef[0],coef[1],coef[2],coef[3]);
            *(float4*)&scl[lane][4] = make_float4(coef[4],coef[5],coef[6],coef[7]);
            *(float2*)&scl[lane][8] = make_float2(mu, rstd);
            *(float4*)(ws + WS_CP + n*8)     = make_float4(coef[0]*invnb,coef[1]*invnb,coef[2]*invnb,coef[3]*invnb);
            *(float4*)(ws + WS_CP + n*8 + 4) = make_float4(coef[4]*invnb,coef[5]*invnb,coef[6]*invnb,coef[7]*invnb);
        }
        #pragma unroll
        for (int off = 16; off >= 1; off >>= 1) {
            csum += __shfl_xor(csum, off, 64);
            dsum += __shfl_xor(dsum, off, 64);
        }
        if (lane == 0) {
            ws[WS_P5A + (size_t)blockIdx.x*2 + 0] = csum;
            ws[WS_P5A + (size_t)blockIdx.x*2 + 1] = dsum;
        }
    }
    __syncthreads();
    // phase B: stream; 8 waves x 4 tokens, two 256-d halves sequentially
    float alpha = alpha_p[0];
    float ng2h[4], dqh[4];
    {
        int d0 = lane*4;
        float4 pbr[8];
        #pragma unroll
        for (int k = 0; k < 8; ++k) pbr[k] = *(const float4*)&pls[k*Dd + d0];
        float4 w4 = *(const float4*)(ln_w + d0);
        float4 b4 = *(const float4*)(ln_b + d0);
        float4 q4 = *(const float4*)(ws + WS_FQN + b*Dd + d0);
        #pragma unroll
        for (int t = 0; t < 4; ++t) {
            int lt = wave*4 + t;
            float4 cA = *(const float4*)&scl[lt][0];
            float4 cB = *(const float4*)&scl[lt][4];
            float2 mr = *(const float2*)&scl[lt][8];
            size_t rowoff = ((size_t)b*Nn + tok0 + lt)*Dd;
            float4 fv = *(const float4*)(f_raw + rowoff + d0);
            float4 fb;
            fb.x = cA.x*pbr[0].x + cA.y*pbr[1].x + cA.z*pbr[2].x + cA.w*pbr[3].x
                 + cB.x*pbr[4].x + cB.y*pbr[5].x + cB.z*pbr[6].x + cB.w*pbr[7].x;
            fb.y = cA.x*pbr[0].y + cA.y*pbr[1].y + cA.z*pbr[2].y + cA.w*pbr[3].y
                 + cB.x*pbr[4].y + cB.y*pbr[5].y + cB.z*pbr[6].y + cB.w*pbr[7].y;
            fb.z = cA.x*pbr[0].z + cA.y*pbr[1].z + cA.z*pbr[2].z + cA.w*pbr[3].z
                 + cB.x*pbr[4].z + cB.y*pbr[5].z + cB.z*pbr[6].z + cB.w*pbr[7].z;
            fb.w = cA.x*pbr[0].w + cA.y*pbr[1].w + cA.z*pbr[2].w + cA.w*pbr[3].w
                 + cB.x*pbr[4].w + cB.y*pbr[5].w + cB.z*pbr[6].w + cB.w*pbr[7].w;
            *(float4*)(out_fbg + rowoff + d0) = fb;
            float4 g;
            g.x = (fv.x - alpha*fb.x - mr.x)*mr.y*w4.x + b4.x;
            g.y = (fv.y - alpha*fb.y - mr.x)*mr.y*w4.y + b4.y;
            g.z = (fv.z - alpha*fb.z - mr.x)*mr.y*w4.z + b4.z;
            g.w = (fv.w - alpha*fb.w - mr.x)*mr.y*w4.w + b4.w;
            *(float4*)(out_ffg + rowoff + d0) = g;
            ng2h[t] = dot4(g, g);
            dqh[t]  = dot4(g, q4);
        }
    }
    float align_s = 0.f, align_c = 0.f;
    {
        int d0 = 256 + lane*4;
        float4 pbr[8];
        #pragma unroll
        for (int k = 0; k < 8; ++k) pbr[k] = *(const float4*)&pls[k*Dd + d0];
        float4 w4 = *(const float4*)(ln_w + d0);
        float4 b4 = *(const float4*)(ln_b + d0);
        float4 q4 = *(const float4*)(ws + WS_FQN + b*Dd + d0);
        #pragma unroll
        for (int t = 0; t < 4; ++t) {
            int lt = wave*4 + t;
            size_t n = (size_t)b*Nn + tok0 + lt;
            float4 cA = *(const float4*)&scl[lt][0];
            float4 cB = *(const float4*)&scl[lt][4];
            float2 mr = *(const float2*)&scl[lt][8];
            size_t rowoff = n*(size_t)Dd;
            float4 fv = *(const float4*)(f_raw + rowoff + d0);
            float4 fb;
            fb.x = cA.x*pbr[0].x + cA.y*pbr[1].x + cA.z*pbr[2].x + cA.w*pbr[3].x
                 + cB.x*pbr[4].x + cB.y*pbr[5].x + cB.z*pbr[6].x + cB.w*pbr[7].x;
            fb.y = cA.x*pbr[0].y + cA.y*pbr[1].y + cA.z*pbr[2].y + cA.w*pbr[3].y
                 + cB.x*pbr[4].y + cB.y*pbr[5].y + cB.z*pbr[6].y + cB.w*pbr[7].y;
            fb.z = cA.x*pbr[0].z + cA.y*pbr[1].z + cA.z*pbr[2].z + cA.w*pbr[3].z
                 + cB.x*pbr[4].z + cB.y*pbr[5].z + cB.z*pbr[6].z + cB.w*pbr[7].z;
            fb.w = cA.x*pbr[0].w + cA.y*pbr[1].w + cA.z*pbr[2].w + cA.w*pbr[3].w
                 + cB.x*pbr[4].w + cB.y*pbr[5].w + cB.z*pbr[6].w + cB.w*pbr[7].w;
            *(float4*)(out_fbg + rowoff + d0) = fb;
            float4 g;
            g.x = (fv.x - alpha*fb.x - mr.x)*mr.y*w4.x + b4.x;
            g.y = (fv.y - alpha*fb.y - mr.x)*mr.y*w4.y + b4.y;
            g.z = (fv.z - alpha*fb.z - mr.x)*mr.y*w4.z + b4.z;
            g.w = (fv.w - alpha*fb.w - mr.x)*mr.y*w4.w + b4.w;
            *(float4*)(out_ffg + rowoff + d0) = g;
            float ng2 = ng2h[t] + dot4(g, g);
            float dq  = dqh[t]  + dot4(g, q4);
            #pragma unroll
            for (int off = 32; off >= 1; off >>= 1) {
                ng2 += __shfl_xor(ng2, off, 64);
                dq  += __shfl_xor(dq,  off, 64);
            }
            float sim = dq * (1.f/fmaxf(sqrtf(ng2), NORM_EPS));
            float ssem = 1.f/(1.f + expf(-sim*(1.f/TAU)));
            if (lane == 0) {
                out_ssem[n] = ssem;
                if (gt_mask[n] != 0) { align_s += -logf(fmaxf(ssem, EPSc)); align_c += 1.f; }
            }
        }
    }
    if (lane == 0) { al[wave][0] = align_s; al[wave][1] = align_c; }
    __syncthreads();
    if (tid == 0) {
        float as = 0.f, ac = 0.f;
        #pragma unroll
        for (int w = 0; w < 8; ++w) { as += al[w][0]; ac += al[w][1]; }
        ws[WS_P5B + (size_t)blockIdx.x*2 + 0] = as;
        ws[WS_P5B + (size_t)blockIdx.x*2 + 1] = ac;
    }
}

// ============ K6s: per-batch S = sum cp cp^T, then tr((M S)^2) ============
__global__ __launch_bounds__(256) void k6s_gram(float* __restrict__ ws) {
    int b = blockIdx.x, tid = threadIdx.x;
    __shared__ float cps[256*8];
    __shared__ float Sred[4][64];
    __shared__ float Sfull[64];
    __shared__ float Alds[64];
    __shared__ float Mlds[64];
    int pr = tid & 63, g = tid >> 6;
    int i = pr >> 3, j = pr & 7;
    float s = 0.f;
    for (int tile = 0; tile < 8; ++tile) {
        __syncthreads();
        #pragma unroll
        for (int q = 0; q < 2; ++q)
            *(float4*)&cps[tid*8 + q*4] =
                *(const float4*)(ws + WS_CP + ((size_t)b*Nn + tile*256)*8 + tid*8 + q*4);
        __syncthreads();
        for (int nn = g*64; nn < g*64 + 64; ++nn)
            s += cps[nn*8 + i]*cps[nn*8 + j];
    }
    Sred[g][pr] = s;
    if (tid < 64) Mlds[tid] = ws[WS_M + b*64 + tid];
    __syncthreads();
    if (tid < 64) Sfull[tid] = Sred[0][tid]+Sred[1][tid]+Sred[2][tid]+Sred[3][tid];
    __syncthreads();
    if (tid < 64) {
        int ii = tid >> 3, jj = tid & 7;
        float a = 0.f;
        #pragma unroll
        for (int k = 0; k < 8; ++k) a += Mlds[ii*8+k]*Sfull[k*8+jj];
        Alds[tid] = a;
    }
    __syncthreads();
    if (tid < 64) {
        float p = Alds[tid]*Alds[(tid & 7)*8 + (tid >> 3)];
        #pragma unroll
        for (int off = 32; off >= 1; off >>= 1) p += __shfl_xor(p, off, 64);
        if (tid == 0) ws[WS_TRB + b] = p;
    }
}

// ============ K7: finalize losses ============
__global__ __launch_bounds__(256) void k7_final(const float* __restrict__ ws,
                                                float* __restrict__ out_loss) {
    int tid = threadIdx.x, lane = tid & 63, wave = tid >> 6;
    __shared__ double red[4][4];
    double c = 0.0, dg = 0.0, as = 0.0, ac = 0.0;
    for (int idx = tid; idx < 1024; idx += 256) {
        c  += (double)ws[WS_P5A + idx*2 + 0];
        dg += (double)ws[WS_P5A + idx*2 + 1];
        as += (double)ws[WS_P5B + idx*2 + 0];
        ac += (double)ws[WS_P5B + idx*2 + 1];
    }
    #pragma unroll
    for (int off = 32; off >= 1; off >>= 1) {
        c  += __shfl_xor(c,  off, 64);
        dg += __shfl_xor(dg, off, 64);
        as += __shfl_xor(as, off, 64);
        ac += __shfl_xor(ac, off, 64);
    }
    if (lane == 0) { red[wave][0]=c; red[wave][1]=dg; red[wave][2]=as; red[wave][3]=ac; }
    __syncthreads();
    if (tid == 0) {
        double ct=0, dgt=0, ast=0, act=0, trt=0;
        for (int w = 0; w < 4; ++w) { ct+=red[w][0]; dgt+=red[w][1]; ast+=red[w][2]; act+=red[w][3]; }
        for (int b = 0; b < Bb; ++b) trt += (double)ws[WS_TRB + b];
        out_loss[0] = (float)(ct / (double)((size_t)Bb*Nn));
        out_loss[1] = (float)((trt - dgt) / ((double)Bb*(double)Nn*(double)Nn));
        out_loss[2] = (float)(act > 0.0 ? ast / (act > 1.0 ? act : 1.0) : 0.0);
    }
}

extern "C" void kernel_launch(void* const* d_in, const int* in_sizes, int n_in,
                              void* d_out, int out_size, void* d_ws, size_t ws_size,
                              hipStream_t stream) {
    (void)in_sizes; (void)n_in; (void)out_size; (void)ws_size;
    const float* f_raw   = (const float*)d_in[0];
    const float* f_q     = (const float*)d_in[1];
    const int*   gt_mask = (const int*)d_in[2];
    const float* q_bg    = (const float*)d_in[3];
    const float* alpha   = (const float*)d_in[4];
    const float* ln_w    = (const float*)d_in[5];
    const float* ln_b    = (const float*)d_in[6];
    float* out = (float*)d_out;
    float* ws  = (float*)d_ws;

    k1_scores<<<Bb*NCH, 512, 0, stream>>>(f_raw, q_bg, ws);
    k3b1_reduce<<<dim3(Bb, Kk), 256, 0, stream>>>(ws, out + OUT_PBG);
    k3b2_stats<<<Bb, 256, 0, stream>>>(ws, out + OUT_PBG, f_q);
    k5_main<<<Bb*NCH, 512, 0, stream>>>(f_raw, gt_mask, alpha, ln_w, ln_b,
                                        out + OUT_PBG, ws,
                                        out + OUT_FFG, out + OUT_FBG, out + OUT_SSEM);
    k6s_gram<<<Bb, 256, 0, stream>>>(ws);
    k7_final<<<1, 256, 0, stream>>>(ws, out + OUT_LOSS);
}